// Round 11
// baseline (109.129 us; speedup 1.0000x reference)
//
#include <hip/hip_runtime.h>

// LSNet collapse: final mask x == 0 everywhere (argmax over identical negsum9
// channels == 0), so the network reduces to:
//   c2  = sum(inp) / 4194304
//   out = tanh( conv3x3x3( c2^2 - 2*c2*inp , c1_w, zero-padded operand ) )
// (biases cancel; out-of-bounds taps contribute exactly 0).
//
// R11: kill the per-block c2-fold preamble (4KB partial load + LDS reduce +
// 2 barriers in EVERY stencil block — constant through R8/R9/R10's neutral
// results, on the critical path before any stencil load can issue). Reduction
// now finishes with one device-scope atomicAdd per block into a single float;
// the stencil reads it with one uniform scalar load. fp32 atomic ordering
// noise (~1e-7 rel) is invisible at the bf16 compare floor (3.9e-3).

#define NVOX (2 * 128 * 128 * 128)   // 4194304

typedef float nfloat4 __attribute__((ext_vector_type(4)));

__global__ __launch_bounds__(256) void k_reduce_partial(const float* __restrict__ inp,
                                                        float* __restrict__ acc) {
    int tid = blockIdx.x * 256 + threadIdx.x;           // 0 .. 262143
    const float4* in4 = (const float4*)inp;
    float s = 0.f;
#pragma unroll
    for (int i = 0; i < 4; ++i) {
        float4 v = in4[tid + i * 262144];
        s += (v.x + v.y) + (v.z + v.w);
    }
#pragma unroll
    for (int off = 32; off > 0; off >>= 1) s += __shfl_down(s, off, 64);
    __shared__ float ws[4];
    int lane = threadIdx.x & 63;
    int wid  = threadIdx.x >> 6;
    if (lane == 0) ws[wid] = s;
    __syncthreads();
    if (threadIdx.x == 0)
        atomicAdd(acc, (ws[0] + ws[1]) + (ws[2] + ws[3]));   // device-scope
}

__device__ __forceinline__ float fast_tanh(float x) {
    float e = __expf(2.f * x);
    return 1.f - 2.f * __builtin_amdgcn_rcpf(e + 1.f);
}

// block = (32, 8): tx = x-quad, ty = h-row PAIR.  grid = (1, 8, 256):
// y: 8 tiles of 16 h-rows; z = n*128 + d plane.
__global__ __launch_bounds__(256) void k_stencil(const float* __restrict__ inp,
                                                 const float* __restrict__ w27,
                                                 const float* __restrict__ accp,
                                                 float* __restrict__ out) {
    const int tx   = threadIdx.x;                 // 0..31
    const int ty   = threadIdx.y;                 // 0..7
    const int lin  = ty * 32 + tx;
    const int lane = lin & 63;

    // c2 via one uniform scalar load — no LDS, no barriers.
    const float c2   = accp[0] * (1.f / (float)NVOX);
    const float c2sq = c2 * c2;
    const float m2c2 = -2.f * c2;

    float wr[27];
#pragma unroll
    for (int i = 0; i < 27; ++i) wr[i] = w27[i];   // uniform -> scalar loads

    const int h0 = blockIdx.y * 16 + ty * 2;      // out rows h0, h0+1 (0..126)
    const int nd = blockIdx.z;                    // global plane, 0..255
    const int d  = nd & 127;

    float4 acc0 = {0.f, 0.f, 0.f, 0.f};          // out row h0
    float4 acc1 = {0.f, 0.f, 0.f, 0.f};          // out row h0+1

#pragma unroll
    for (int p = -1; p <= 1; ++p) {               // dz
        const bool vz = (unsigned)(d + p) < 128u;
        const int  pz = vz ? (nd + p) : nd;       // clamped plane
        const float* pb = inp + ((size_t)pz << 14);

        // load 4 rows of this plane upfront (h0-1 .. h0+2), branch-free
        float4 v[4];
        float  mk[4];
#pragma unroll
        for (int j = 0; j < 4; ++j) {
            const int  hr = h0 - 1 + j;
            const bool vy = (unsigned)hr < 128u;
            const int  hc = vy ? hr : h0;         // clamped row
            mk[j] = (vz && vy) ? 1.f : 0.f;
            v[j] = ((const float4*)(pb + (hc << 7)))[tx];
        }

        // transform + x-halo per row, then accumulate into both outputs
        float4 t[4];
        float  tl[4], tr[4];
#pragma unroll
        for (int j = 0; j < 4; ++j) {
            const float m = mk[j];
            t[j].x = m * fmaf(m2c2, v[j].x, c2sq);
            t[j].y = m * fmaf(m2c2, v[j].y, c2sq);
            t[j].z = m * fmaf(m2c2, v[j].z, c2sq);
            t[j].w = m * fmaf(m2c2, v[j].w, c2sq);
            float L = __shfl(t[j].w, (lane - 1) & 63, 64);
            float R = __shfl(t[j].x, (lane + 1) & 63, 64);
            tl[j] = (tx == 0)  ? 0.f : L;
            tr[j] = (tx == 31) ? 0.f : R;
        }

        const int r0 = (p + 1) * 9;
#pragma unroll
        for (int dy = 0; dy < 3; ++dy) {
            const int r = r0 + dy * 3;
            const float w0 = wr[r], w1 = wr[r + 1], w2 = wr[r + 2];
            // out row h0 uses rows j = dy
            {
                const float4& q = t[dy];
                acc0.x = fmaf(w0, tl[dy], fmaf(w1, q.x, fmaf(w2, q.y, acc0.x)));
                acc0.y = fmaf(w0, q.x,    fmaf(w1, q.y, fmaf(w2, q.z, acc0.y)));
                acc0.z = fmaf(w0, q.y,    fmaf(w1, q.z, fmaf(w2, q.w, acc0.z)));
                acc0.w = fmaf(w0, q.z,    fmaf(w1, q.w, fmaf(w2, tr[dy], acc0.w)));
            }
            // out row h0+1 uses rows j = dy+1
            {
                const float4& q = t[dy + 1];
                acc1.x = fmaf(w0, tl[dy + 1], fmaf(w1, q.x, fmaf(w2, q.y, acc1.x)));
                acc1.y = fmaf(w0, q.x,        fmaf(w1, q.y, fmaf(w2, q.z, acc1.y)));
                acc1.z = fmaf(w0, q.y,        fmaf(w1, q.z, fmaf(w2, q.w, acc1.z)));
                acc1.w = fmaf(w0, q.z,        fmaf(w1, q.w, fmaf(w2, tr[dy + 1], acc1.w)));
            }
        }
    }

    nfloat4 o0, o1;
    o0.x = fast_tanh(acc0.x); o0.y = fast_tanh(acc0.y);
    o0.z = fast_tanh(acc0.z); o0.w = fast_tanh(acc0.w);
    o1.x = fast_tanh(acc1.x); o1.y = fast_tanh(acc1.y);
    o1.z = fast_tanh(acc1.z); o1.w = fast_tanh(acc1.w);

    float* obase = out + ((size_t)nd << 14) + (h0 << 7);
    __builtin_nontemporal_store(o0, reinterpret_cast<nfloat4*>(obase) + tx);
    __builtin_nontemporal_store(o1, reinterpret_cast<nfloat4*>(obase + 128) + tx);
}

extern "C" void kernel_launch(void* const* d_in, const int* in_sizes, int n_in,
                              void* d_out, int out_size, void* d_ws, size_t ws_size,
                              hipStream_t stream) {
    // inputs: 0=x, 1=inp, 2=conv_w, 3=conv_b, 4=bn_g, 5=bn_b, 6=c1_w, 7=c1_b
    const float* inp = (const float*)d_in[1];
    const float* c1w = (const float*)d_in[6];
    float* out = (float*)d_out;

    float* acc = (float*)d_ws;   // single-float sum accumulator

    hipMemsetAsync(acc, 0, sizeof(float), stream);   // graph-capturable memset node
    hipLaunchKernelGGL(k_reduce_partial, dim3(1024), dim3(256), 0, stream, inp, acc);

    dim3 blk(32, 8, 1);
    dim3 grd(1, 8, 256);
    hipLaunchKernelGGL(k_stencil, grd, blk, 0, stream, inp, c1w, acc, out);
}

// Round 12
// 97.099 us; speedup vs baseline: 1.1239x; 1.1239x over previous
//
#include <hip/hip_runtime.h>

// LSNet collapse: final mask x == 0 everywhere (argmax over identical negsum9
// channels == 0), so the network reduces to:
//   c2  = sum(inp) / 4194304
//   out = tanh( conv3x3x3( c2^2 - 2*c2*inp , c1_w, zero-padded operand ) )
// (biases cancel; out-of-bounds taps contribute exactly 0).
//
// R12 = R8 verbatim (best measured: 97.0 µs). R9 (-25% VALU), R10 (-33%
// loads/shfl), R11 (atomic c2, +1 node) were neutral/regression — the
// two-dispatch structure with in-stencil c2 fold is the empirical optimum;
// the timed window is ~83% harness restore fills (BW-bound at 76-80% peak).

#define NVOX (2 * 128 * 128 * 128)   // 4194304

typedef float nfloat4 __attribute__((ext_vector_type(4)));

__global__ __launch_bounds__(256) void k_reduce_partial(const float* __restrict__ inp,
                                                        float* __restrict__ partial) {
    int tid = blockIdx.x * 256 + threadIdx.x;           // 0 .. 262143
    const float4* in4 = (const float4*)inp;
    float s = 0.f;
#pragma unroll
    for (int i = 0; i < 4; ++i) {
        float4 v = in4[tid + i * 262144];
        s += (v.x + v.y) + (v.z + v.w);
    }
#pragma unroll
    for (int off = 32; off > 0; off >>= 1) s += __shfl_down(s, off, 64);
    __shared__ float ws[4];
    int lane = threadIdx.x & 63;
    int wid  = threadIdx.x >> 6;
    if (lane == 0) ws[wid] = s;
    __syncthreads();
    if (threadIdx.x == 0) partial[blockIdx.x] = (ws[0] + ws[1]) + (ws[2] + ws[3]);
}

__device__ __forceinline__ float fast_tanh(float x) {
    float e = __expf(2.f * x);
    return 1.f - 2.f * __builtin_amdgcn_rcpf(e + 1.f);
}

// block = (32, 8): tx = x-quad, ty = h row.  grid = (1, 16, 256):
// y: 16 h-tiles of 8; z = n*128 + d plane.
__global__ __launch_bounds__(256) void k_stencil(const float* __restrict__ inp,
                                                 const float* __restrict__ w27,
                                                 const float* __restrict__ partial,
                                                 float* __restrict__ out) {
    const int tx   = threadIdx.x;                 // 0..31
    const int ty   = threadIdx.y;                 // 0..7
    const int lin  = ty * 32 + tx;
    const int lane = lin & 63;

    // ---- fold final reduction: sum 1024 partials (4 KB, L2-hot) ----
    __shared__ float ws[4];
    __shared__ float c2sh;
    {
        const float4* p4 = (const float4*)partial;   // 256 float4
        float4 v = p4[lin];
        float s = (v.x + v.y) + (v.z + v.w);
#pragma unroll
        for (int off = 32; off > 0; off >>= 1) s += __shfl_down(s, off, 64);
        if (lane == 0) ws[lin >> 6] = s;
        __syncthreads();
        if (lin == 0) c2sh = ((ws[0] + ws[1]) + (ws[2] + ws[3])) / (float)NVOX;
        __syncthreads();
    }
    const float c2   = c2sh;
    const float c2sq = c2 * c2;
    const float m2c2 = -2.f * c2;

    float wr[27];
#pragma unroll
    for (int i = 0; i < 27; ++i) wr[i] = w27[i];

    const int h  = blockIdx.y * 8 + ty;           // 0..127
    const int nd = blockIdx.z;                    // global plane, 0..255
    const int d  = nd & 127;

    // ---- issue all 9 row loads upfront, branch-free ----
    float4 v[9];
    float  msk[9];
#pragma unroll
    for (int dz = -1; dz <= 1; ++dz) {
        const bool vz = (unsigned)(d + dz) < 128u;
        const int  pz = vz ? (nd + dz) : nd;      // clamped plane
#pragma unroll
        for (int dy = -1; dy <= 1; ++dy) {
            const int  h2 = h + dy;
            const bool vy = (unsigned)h2 < 128u;
            const int  hc = vy ? h2 : h;          // clamped row
            const int  idx = (dz + 1) * 3 + (dy + 1);
            msk[idx] = (vz && vy) ? 1.f : 0.f;
            v[idx] = ((const float4*)(inp + ((size_t)pz << 14) + (hc << 7)))[tx];
        }
    }

    // ---- transform, mask, gather x-halo, accumulate ----
    float4 acc = {0.f, 0.f, 0.f, 0.f};
#pragma unroll
    for (int idx = 0; idx < 9; ++idx) {
        const float m = msk[idx];
        float4 t;
        t.x = m * fmaf(m2c2, v[idx].x, c2sq);
        t.y = m * fmaf(m2c2, v[idx].y, c2sq);
        t.z = m * fmaf(m2c2, v[idx].z, c2sq);
        t.w = m * fmaf(m2c2, v[idx].w, c2sq);
        float tL = __shfl(t.w, (lane - 1) & 63, 64);
        float tR = __shfl(t.x, (lane + 1) & 63, 64);
        if (tx == 0)  tL = 0.f;
        if (tx == 31) tR = 0.f;
        const int r = idx * 3;                    // (dz+1)*9 + (dy+1)*3
        const float w0 = wr[r], w1 = wr[r + 1], w2 = wr[r + 2];
        acc.x = fmaf(w0, tL,  fmaf(w1, t.x, fmaf(w2, t.y, acc.x)));
        acc.y = fmaf(w0, t.x, fmaf(w1, t.y, fmaf(w2, t.z, acc.y)));
        acc.z = fmaf(w0, t.y, fmaf(w1, t.z, fmaf(w2, t.w, acc.z)));
        acc.w = fmaf(w0, t.z, fmaf(w1, t.w, fmaf(w2, tR,  acc.w)));
    }

    nfloat4 o;
    o.x = fast_tanh(acc.x);
    o.y = fast_tanh(acc.y);
    o.z = fast_tanh(acc.z);
    o.w = fast_tanh(acc.w);
    nfloat4* out4 = reinterpret_cast<nfloat4*>(out + ((size_t)nd << 14) + (h << 7));
    __builtin_nontemporal_store(o, out4 + tx);    // streamed; don't pollute L2
}

extern "C" void kernel_launch(void* const* d_in, const int* in_sizes, int n_in,
                              void* d_out, int out_size, void* d_ws, size_t ws_size,
                              hipStream_t stream) {
    // inputs: 0=x, 1=inp, 2=conv_w, 3=conv_b, 4=bn_g, 5=bn_b, 6=c1_w, 7=c1_b
    const float* inp = (const float*)d_in[1];
    const float* c1w = (const float*)d_in[6];
    float* out = (float*)d_out;

    float* partial = (float*)d_ws;   // 1024 floats

    hipLaunchKernelGGL(k_reduce_partial, dim3(1024), dim3(256), 0, stream, inp, partial);

    dim3 blk(32, 8, 1);
    dim3 grd(1, 16, 256);
    hipLaunchKernelGGL(k_stencil, grd, blk, 0, stream, inp, c1w, partial, out);
}